// Round 11
// baseline (410.310 us; speedup 1.0000x reference)
//
#include <hip/hip_runtime.h>
#include <hip/hip_bf16.h>

#define NVOX 200000
#define CO 64

typedef short short8 __attribute__((ext_vector_type(8)));
typedef float f32x4 __attribute__((ext_vector_type(4)));

static __device__ __forceinline__ short f2bf(float f) {
    __hip_bfloat16 h = __float2bfloat16(f);
    return __builtin_bit_cast(short, h);
}
static __device__ __forceinline__ float bfu(unsigned short u) {
    union { unsigned int i; float f; } x; x.i = ((unsigned int)u) << 16; return x.f;
}

// Implicit-GEMM submanifold sparse conv via MFMA 16x16x32 bf16.
// One wave owns 32 voxels = 2 M-tiles of 16; 6250 waves per branch; both
// branches in ONE dispatch (blockIdx.y). nbr indices preloaded; k-loop fully
// unrolled so the compiler keeps multiple k of gathers in flight.
// Stats: wave shfl-reduce -> LDS block-reduce -> per-block partial write
// (NO atomics; a separate kernel reduces the 1250 partials per branch).
template<int CIN, bool LRELU, bool BIAS, bool OUT0_BF16, bool OUT1_BF16>
__global__ __launch_bounds__(320, 4) void conv_mfma2(
    const unsigned short* __restrict__ xin0, const unsigned short* __restrict__ xin1,
    const int*  __restrict__ nbr0, const int* __restrict__ nbr1,
    const unsigned short* __restrict__ pack0, const unsigned short* __restrict__ pack1,
    const unsigned short* __restrict__ biasB0, const unsigned short* __restrict__ biasB1,
    void* __restrict__ out0, void* __restrict__ out1,
    float* __restrict__ parts)                     // [2*1250][128]
{
    constexpr int CHN = CIN / 32;
    const int br = blockIdx.y;
    const unsigned short* xin    = br ? xin1 : xin0;
    const int* nbr               = br ? nbr1 : nbr0;
    const unsigned short* bpack  = br ? pack1 : pack0;
    const unsigned short* biasB  = br ? biasB1 : biasB0;
    void* outp                   = br ? out1 : out0;
    const bool OUT_BF16          = br ? OUT1_BF16 : OUT0_BF16;

    const int lane = threadIdx.x & 63;
    const int wblk = threadIdx.x >> 6;            // 0..4 (5 waves/block)
    const int wv   = blockIdx.x * 5 + wblk;       // 0..6249, exact
    const int gbase = wv * 32;                    // 32 voxels per wave
    const int g = lane >> 4, r16 = lane & 15;

    // Preload all neighbor indices.
    int iv[2][9];
    #pragma unroll
    for (int t = 0; t < 2; ++t)
        #pragma unroll
        for (int k = 0; k < 9; ++k)
            iv[t][k] = nbr[k * NVOX + gbase + t * 16 + r16];

    f32x4 acc[2][4];
    #pragma unroll
    for (int t = 0; t < 2; ++t)
        #pragma unroll
        for (int nt = 0; nt < 4; ++nt)
            acc[t][nt] = (f32x4){0.f, 0.f, 0.f, 0.f};

    #pragma unroll
    for (int k = 0; k < 9; ++k) {
        short8 bf[CHN][4];
        #pragma unroll
        for (int ch = 0; ch < CHN; ++ch)
            #pragma unroll
            for (int nt = 0; nt < 4; ++nt)
                bf[ch][nt] = *reinterpret_cast<const short8*>(
                    bpack + ((((size_t)k * CHN + ch) * 4 + nt) * 64 + lane) * 8);
        #pragma unroll
        for (int t = 0; t < 2; ++t) {
            const int ivk = iv[t][k];
            const int ivt = ivk < 0 ? 0 : ivk;
            #pragma unroll
            for (int ch = 0; ch < CHN; ++ch) {
                short8 av = *reinterpret_cast<const short8*>(
                    xin + (size_t)ivt * CIN + ch * 32 + g * 8);
                if (ivk < 0) { short8 z = {0,0,0,0,0,0,0,0}; av = z; }
                #pragma unroll
                for (int nt = 0; nt < 4; ++nt)
                    acc[t][nt] = __builtin_amdgcn_mfma_f32_16x16x32_bf16(av, bf[ch][nt], acc[t][nt], 0, 0, 0);
            }
        }
    }

    if (BIAS) {
        short8 bb[4];
        #pragma unroll
        for (int nt = 0; nt < 4; ++nt)
            bb[nt] = *reinterpret_cast<const short8*>(biasB + ((size_t)nt * 64 + lane) * 8);
        #pragma unroll
        for (int t = 0; t < 2; ++t) {
            unsigned vmask = 0;
            #pragma unroll
            for (int k = 0; k < 9; ++k) vmask |= (iv[t][k] >= 0 ? 1u : 0u) << k;
            short8 vf;
            #pragma unroll
            for (int i = 0; i < 8; ++i) {
                int k9 = g * 8 + i;
                vf[i] = (k9 < 9 && ((vmask >> k9) & 1u)) ? (short)0x3F80 : (short)0;
            }
            #pragma unroll
            for (int nt = 0; nt < 4; ++nt)
                acc[t][nt] = __builtin_amdgcn_mfma_f32_16x16x32_bf16(vf, bb[nt], acc[t][nt], 0, 0, 0);
        }
    }

    // Epilogue: lrelu, store, per-channel stats.
    float ss[4] = {0,0,0,0}, sq[4] = {0,0,0,0};
    #pragma unroll
    for (int t = 0; t < 2; ++t)
        #pragma unroll
        for (int nt = 0; nt < 4; ++nt)
            #pragma unroll
            for (int rr = 0; rr < 4; ++rr) {
                float val = acc[t][nt][rr];
                if (LRELU) val = val > 0.f ? val : 0.01f * val;
                ss[nt] += val; sq[nt] += val * val;
                const size_t o = (size_t)(gbase + t * 16 + g * 4 + rr) * CO + nt * 16 + r16;
                if (OUT_BF16) ((__hip_bfloat16*)outp)[o] = __float2bfloat16(val);
                else          ((float*)outp)[o] = val;
            }

    // Wave reduce (4 lane-groups sharing r16) -> LDS block reduce ->
    // per-block partial write (no atomics).
    __shared__ float lsum[5][64];
    __shared__ float lsq[5][64];
    #pragma unroll
    for (int nt = 0; nt < 4; ++nt) {
        float a = ss[nt], b = sq[nt];
        a += __shfl_xor(a, 16); a += __shfl_xor(a, 32);
        b += __shfl_xor(b, 16); b += __shfl_xor(b, 32);
        if (lane < 16) { lsum[wblk][nt * 16 + r16] = a; lsq[wblk][nt * 16 + r16] = b; }
    }
    __syncthreads();
    if (threadIdx.x < 64) {
        float a = 0.f, b = 0.f;
        #pragma unroll
        for (int w = 0; w < 5; ++w) { a += lsum[w][threadIdx.x]; b += lsq[w][threadIdx.x]; }
        float* dst = parts + ((size_t)blockIdx.y * gridDim.x + blockIdx.x) * 128;
        dst[threadIdx.x] = a;
        dst[64 + threadIdx.x] = b;
    }
}

// f32 [N][32] -> bf16 [N][32] (one-shot pre-cast for conv1 gathers)
__global__ __launch_bounds__(256) void cast_feats(const float* __restrict__ in,
                                                  unsigned short* __restrict__ outp)
{
    const int i = (blockIdx.x * 256 + threadIdx.x) * 8;
    float4 f0 = ((const float4*)(in + i))[0];
    float4 f1 = ((const float4*)(in + i))[1];
    short8 v;
    v[0] = f2bf(f0.x); v[1] = f2bf(f0.y); v[2] = f2bf(f0.z); v[3] = f2bf(f0.w);
    v[4] = f2bf(f1.x); v[5] = f2bf(f1.y); v[6] = f2bf(f1.z); v[7] = f2bf(f1.w);
    *reinterpret_cast<short8*>(outp + i) = v;
}

// Pack conv1 weights (f32 [9][32][64]) into B-fragment layout bf16.
__global__ void prepack_w32(const float* __restrict__ W1, const float* __restrict__ W2,
                            unsigned short* __restrict__ P1, unsigned short* __restrict__ P2)
{
    int s = blockIdx.x / 9, k = blockIdx.x % 9, l = threadIdx.x;
    const float* W = s ? W2 : W1;
    unsigned short* P = s ? P2 : P1;
    int g = l >> 4, r16 = l & 15;
    for (int nt = 0; nt < 4; ++nt)
        for (int i = 0; i < 8; ++i) {
            int c = g * 8 + i, j = nt * 16 + r16;
            P[(((size_t)k * 4 + nt) * 64 + l) * 8 + i] =
                (unsigned short)f2bf(W[((size_t)k * 32 + c) * 64 + j]);
        }
}

// Reduce 1250 per-block partials per branch, then BN finalize (a, c).
__global__ __launch_bounds__(512) void bn_reduce_fin(
    const float* __restrict__ parts,   // [2][1250][128]
    const float* g_0, const float* b_0, float* a_0, float* c_0,
    const float* g_1, const float* b_1, float* a_1, float* c_1)
{
    const int br = blockIdx.x;
    const float* P = parts + (size_t)br * 1250 * 128;
    const int tid = threadIdx.x;
    const int col = tid & 127, seg = tid >> 7;
    float s = 0.f;
    for (int i = seg; i < 1250; i += 4) s += P[(size_t)i * 128 + col];
    __shared__ float red[4][128];
    red[seg][col] = s;
    __syncthreads();
    if (seg == 0) red[0][col] = red[0][col] + red[1][col] + red[2][col] + red[3][col];
    __syncthreads();
    if (tid < 64) {
        const float inv_n = 1.f / (float)NVOX;
        float m = red[0][tid] * inv_n;
        float v = red[0][64 + tid] * inv_n - m * m;
        const float* g = br ? g_1 : g_0;
        const float* b = br ? b_1 : b_0;
        float* a = br ? a_1 : a_0;
        float* c = br ? c_1 : c_0;
        float av = g[tid] * rsqrtf(v + 1e-5f);
        a[tid] = av;
        c[tid] = b[tid] - m * av;
    }
}

// Fold BN affine into conv2 weights, emit packed bf16 B-fragments + f32 bias.
__global__ void wtrans(const float* W0, const float* a0v, const float* c0v, unsigned short* P0, float* bias0,
                       const float* W1, const float* a1v, const float* c1v, unsigned short* P1, float* bias1)
{
    int s = blockIdx.x / 9, k = blockIdx.x % 9, l = threadIdx.x;
    const float* W  = s ? W1 : W0;
    const float* av = s ? a1v : a0v;
    const float* cv = s ? c1v : c0v;
    unsigned short* P = s ? P1 : P0;
    float* bias = s ? bias1 : bias0;
    int g = l >> 4, r16 = l & 15;
    for (int ch = 0; ch < 2; ++ch)
        for (int nt = 0; nt < 4; ++nt)
            for (int i = 0; i < 8; ++i) {
                int c = ch * 32 + g * 8 + i, j = nt * 16 + r16;
                P[((((size_t)k * 2 + ch) * 4 + nt) * 64 + l) * 8 + i] =
                    (unsigned short)f2bf(av[c] * W[((size_t)k * 64 + c) * 64 + j]);
            }
    float bs = 0.f;
    for (int c = 0; c < 64; ++c) bs += cv[c] * W[((size_t)k * 64 + c) * 64 + l];
    bias[k * 64 + l] = bs;
}

// Pack bias [9][64] f32 into validity-MFMA B-fragment layout (K=32, 9 live rows).
__global__ void wpack_bias(const float* bias0, unsigned short* B0,
                           const float* bias1, unsigned short* B1)
{
    int s = blockIdx.x, l = threadIdx.x;
    const float* bias = s ? bias1 : bias0;
    unsigned short* B = s ? B1 : B0;
    int g = l >> 4, r16 = l & 15;
    for (int nt = 0; nt < 4; ++nt)
        for (int i = 0; i < 8; ++i) {
            int k9 = g * 8 + i;
            B[((size_t)nt * 64 + l) * 8 + i] =
                k9 < 9 ? (unsigned short)f2bf(bias[k9 * 64 + nt * 16 + r16]) : (unsigned short)0;
        }
}

// out = a2*r2 + c2 + a02*sc2 + c02, 8 elements per thread (vectorized).
__global__ __launch_bounds__(256) void final_k8(
    float* __restrict__ out, const __hip_bfloat16* __restrict__ sc2,
    const float* __restrict__ a2, const float* __restrict__ c2,
    const float* __restrict__ a02, const float* __restrict__ c02)
{
    const int i = (blockIdx.x * 256 + threadIdx.x) * 8;
    const int ch0 = i & 63;                      // multiple of 8
    float4 r0 = ((const float4*)(out + i))[0];
    float4 r1 = ((const float4*)(out + i))[1];
    short8 s = *reinterpret_cast<const short8*>((const unsigned short*)sc2 + i);
    float rr[8] = {r0.x, r0.y, r0.z, r0.w, r1.x, r1.y, r1.z, r1.w};
    float res[8];
    #pragma unroll
    for (int j = 0; j < 8; ++j) {
        int ch = ch0 + j;
        res[j] = a2[ch] * rr[j] + c2[ch] + a02[ch] * bfu((unsigned short)s[j]) + c02[ch];
    }
    float4 o0 = {res[0], res[1], res[2], res[3]};
    float4 o1 = {res[4], res[5], res[6], res[7]};
    ((float4*)(out + i))[0] = o0;
    ((float4*)(out + i))[1] = o1;
}

extern "C" void kernel_launch(void* const* d_in, const int* in_sizes, int n_in,
                              void* d_out, int out_size, void* d_ws, size_t ws_size,
                              hipStream_t stream)
{
    const float* feats = (const float*)d_in[0];
    const int*   nbr_a = (const int*)d_in[1];
    const int*   nbr_b = (const int*)d_in[2];
    const float* W1    = (const float*)d_in[3];
    const float* W1_2  = (const float*)d_in[4];
    const float* W2    = (const float*)d_in[5];
    const float* W3    = (const float*)d_in[6];
    const float* g0    = (const float*)d_in[7];
    const float* b0    = (const float*)d_in[8];
    const float* g0_2  = (const float*)d_in[9];
    const float* b0_2  = (const float*)d_in[10];
    const float* g1    = (const float*)d_in[11];
    const float* b1    = (const float*)d_in[12];
    const float* g2    = (const float*)d_in[13];
    const float* b2    = (const float*)d_in[14];

    char* ws = (char*)d_ws;
    size_t off = 0;
    auto alloc = [&](size_t bytes) { void* p = ws + off; off += (bytes + 255) & ~(size_t)255; return p; };
    __hip_bfloat16* sc1 = (__hip_bfloat16*)alloc((size_t)NVOX * CO * 2);
    __hip_bfloat16* r1  = (__hip_bfloat16*)alloc((size_t)NVOX * CO * 2);
    __hip_bfloat16* sc2 = (__hip_bfloat16*)alloc((size_t)NVOX * CO * 2);
    // bf16 feats (12.8 MB) aliased into sc2's buffer (25.6 MB): read only during
    // pass 1; sc2 is fully overwritten by pass 2 afterwards.
    unsigned short* featsbf = (unsigned short*)sc2;
    unsigned short* P1a = (unsigned short*)alloc((size_t)9 * 4 * 64 * 8 * 2);       // conv1 sc weights
    unsigned short* P1b = (unsigned short*)alloc((size_t)9 * 4 * 64 * 8 * 2);       // conv1 r weights
    unsigned short* P2a = (unsigned short*)alloc((size_t)9 * 2 * 4 * 64 * 8 * 2);   // conv2 sc folded
    unsigned short* P2b = (unsigned short*)alloc((size_t)9 * 2 * 4 * 64 * 8 * 2);   // conv2 r folded
    unsigned short* Bba = (unsigned short*)alloc((size_t)4 * 64 * 8 * 2);           // bias frags sc
    unsigned short* Bbb = (unsigned short*)alloc((size_t)4 * 64 * 8 * 2);           // bias frags r
    float* bias_sc = (float*)alloc(9 * 64 * 4);
    float* bias_r  = (float*)alloc(9 * 64 * 4);
    float* parts1  = (float*)alloc((size_t)2 * 1250 * 128 * 4);
    float* parts2  = (float*)alloc((size_t)2 * 1250 * 128 * 4);
    float* bn = (float*)alloc(8 * 64 * 4);
    float* a0 = bn,        *c0 = bn + 64;
    float* a1 = bn + 128,  *c1 = bn + 192;
    float* a02 = bn + 256, *c02 = bn + 320;
    float* a2 = bn + 384,  *c2 = bn + 448;

    const dim3 cgrid(1250, 2);   // 6250 waves per branch x 2 branches, exact
    const dim3 cblk(320);        // 5 waves per block

    cast_feats<<<3125, 256, 0, stream>>>(feats, featsbf);
    prepack_w32<<<18, 64, 0, stream>>>(W1, W2, P1a, P1b);

    // pass 1: conv1 both branches (bf16 input, lrelu, partial stats)
    conv_mfma2<32, true, false, true, true><<<cgrid, cblk, 0, stream>>>(
        featsbf, featsbf, nbr_a, nbr_b, P1a, P1b, nullptr, nullptr,
        sc1, r1, parts1);
    // BN1 reduce+finalize, fold into conv2 weights, pack bias frags
    bn_reduce_fin<<<2, 512, 0, stream>>>(parts1, g0, b0, a0, c0, g1, b1, a1, c1);
    wtrans<<<18, 64, 0, stream>>>(W1_2, a0, c0, P2a, bias_sc, W3, a1, c1, P2b, bias_r);
    wpack_bias<<<2, 64, 0, stream>>>(bias_sc, Bba, bias_r, Bbb);
    // pass 2: conv2 both branches (bf16 input, bias, partial stats)
    conv_mfma2<64, false, true, true, false><<<cgrid, cblk, 0, stream>>>(
        (const unsigned short*)sc1, (const unsigned short*)r1, nbr_b, nbr_a,
        P2a, P2b, Bba, Bbb, sc2, d_out, parts2);
    // BN2 reduce+finalize + final fused add
    bn_reduce_fin<<<2, 512, 0, stream>>>(parts2, g0_2, b0_2, a02, c02, g2, b2, a2, c2);
    final_k8<<<6250, 256, 0, stream>>>((float*)d_out, sc2, a2, c2, a02, c02);
}

// Round 12
// 301.743 us; speedup vs baseline: 1.3598x; 1.3598x over previous
//
#include <hip/hip_runtime.h>
#include <hip/hip_bf16.h>

#define NVOX 200000
#define CO 64
#define GX 1256          // 8 XCDs x 157 logical blocks (1250 live + 6 empty)
#define CPX 157

typedef short short8 __attribute__((ext_vector_type(8)));
typedef float f32x4 __attribute__((ext_vector_type(4)));

static __device__ __forceinline__ short f2bf(float f) {
    __hip_bfloat16 h = __float2bfloat16(f);
    return __builtin_bit_cast(short, h);
}
static __device__ __forceinline__ float bfu(unsigned short u) {
    union { unsigned int i; float f; } x; x.i = ((unsigned int)u) << 16; return x.f;
}

// Implicit-GEMM submanifold sparse conv via MFMA 16x16x32 bf16.
// One wave owns 32 voxels = 2 M-tiles; 6250 live waves per branch; both
// branches in ONE dispatch (blockIdx.y). XCD-chunked swizzle: physical block
// x -> xcd = x%8 (1256%8==0 so flat dispatch parity is stable across y),
// logical block = xcd*157 + x/8 -> each XCD's blocks gather from a contiguous
// ~3.2MB voxel slab that fits its private 4MB L2.
// Gathers batch-issued 9-deep per (ch,t) phase for structural MLP.
template<int CIN, bool LRELU, bool BIAS, bool OUT0_BF16, bool OUT1_BF16>
__global__ __launch_bounds__(320, 4) void conv_mfma2(
    const unsigned short* __restrict__ xin0, const unsigned short* __restrict__ xin1,
    const int*  __restrict__ nbr0, const int* __restrict__ nbr1,
    const unsigned short* __restrict__ pack0, const unsigned short* __restrict__ pack1,
    const unsigned short* __restrict__ biasB0, const unsigned short* __restrict__ biasB1,
    void* __restrict__ out0, void* __restrict__ out1,
    float* __restrict__ parts)                     // [2][GX][128]
{
    constexpr int CHN = CIN / 32;
    const int br = blockIdx.y;
    const unsigned short* xin    = br ? xin1 : xin0;
    const int* nbr               = br ? nbr1 : nbr0;
    const unsigned short* bpack  = br ? pack1 : pack0;
    const unsigned short* biasB  = br ? biasB1 : biasB0;
    void* outp                   = br ? out1 : out0;
    const bool OUT_BF16          = br ? OUT1_BF16 : OUT0_BF16;

    const int lblk = (blockIdx.x & 7) * CPX + (blockIdx.x >> 3);   // [0,1256)
    float* dstparts = parts + ((size_t)br * GX + lblk) * 128;
    if (lblk >= 1250) {                       // empty logical block: zero partials
        if (threadIdx.x < 64) { dstparts[threadIdx.x] = 0.f; dstparts[64 + threadIdx.x] = 0.f; }
        return;
    }

    const int lane = threadIdx.x & 63;
    const int wblk = threadIdx.x >> 6;            // 0..4 (5 waves/block)
    const int gbase = (lblk * 5 + wblk) * 32;     // 32 voxels per wave
    const int g = lane >> 4, r16 = lane & 15;

    int iv[2][9];
    #pragma unroll
    for (int t = 0; t < 2; ++t)
        #pragma unroll
        for (int k = 0; k < 9; ++k)
            iv[t][k] = nbr[k * NVOX + gbase + t * 16 + r16];

    f32x4 acc[2][4];
    #pragma unroll
    for (int t = 0; t < 2; ++t)
        #pragma unroll
        for (int nt = 0; nt < 4; ++nt)
            acc[t][nt] = (f32x4){0.f, 0.f, 0.f, 0.f};

    #pragma unroll
    for (int ch = 0; ch < CHN; ++ch) {
        #pragma unroll
        for (int t = 0; t < 2; ++t) {
            // Batch-issue 9 gathers (structural MLP), then zero-fill invalid.
            short8 av[9];
            #pragma unroll
            for (int k = 0; k < 9; ++k) {
                const int ivk = iv[t][k];
                const int ivt = ivk < 0 ? 0 : ivk;
                av[k] = *reinterpret_cast<const short8*>(
                    xin + (size_t)ivt * CIN + ch * 32 + g * 8);
            }
            #pragma unroll
            for (int k = 0; k < 9; ++k)
                if (iv[t][k] < 0) { short8 z = {0,0,0,0,0,0,0,0}; av[k] = z; }
            #pragma unroll
            for (int k = 0; k < 9; ++k) {
                short8 bf[4];
                #pragma unroll
                for (int nt = 0; nt < 4; ++nt)
                    bf[nt] = *reinterpret_cast<const short8*>(
                        bpack + ((((size_t)k * CHN + ch) * 4 + nt) * 64 + lane) * 8);
                #pragma unroll
                for (int nt = 0; nt < 4; ++nt)
                    acc[t][nt] = __builtin_amdgcn_mfma_f32_16x16x32_bf16(av[k], bf[nt], acc[t][nt], 0, 0, 0);
            }
        }
    }

    if (BIAS) {
        short8 bb[4];
        #pragma unroll
        for (int nt = 0; nt < 4; ++nt)
            bb[nt] = *reinterpret_cast<const short8*>(biasB + ((size_t)nt * 64 + lane) * 8);
        #pragma unroll
        for (int t = 0; t < 2; ++t) {
            unsigned vmask = 0;
            #pragma unroll
            for (int k = 0; k < 9; ++k) vmask |= (iv[t][k] >= 0 ? 1u : 0u) << k;
            short8 vf;
            #pragma unroll
            for (int i = 0; i < 8; ++i) {
                int k9 = g * 8 + i;
                vf[i] = (k9 < 9 && ((vmask >> k9) & 1u)) ? (short)0x3F80 : (short)0;
            }
            #pragma unroll
            for (int nt = 0; nt < 4; ++nt)
                acc[t][nt] = __builtin_amdgcn_mfma_f32_16x16x32_bf16(vf, bb[nt], acc[t][nt], 0, 0, 0);
        }
    }

    // Epilogue: lrelu, store, per-channel stats.
    float ss[4] = {0,0,0,0}, sq[4] = {0,0,0,0};
    #pragma unroll
    for (int t = 0; t < 2; ++t)
        #pragma unroll
        for (int nt = 0; nt < 4; ++nt)
            #pragma unroll
            for (int rr = 0; rr < 4; ++rr) {
                float val = acc[t][nt][rr];
                if (LRELU) val = val > 0.f ? val : 0.01f * val;
                ss[nt] += val; sq[nt] += val * val;
                const size_t o = (size_t)(gbase + t * 16 + g * 4 + rr) * CO + nt * 16 + r16;
                if (OUT_BF16) ((__hip_bfloat16*)outp)[o] = __float2bfloat16(val);
                else          ((float*)outp)[o] = val;
            }

    // Wave shfl-reduce -> LDS block reduce -> per-block partial write.
    __shared__ float lsum[5][64];
    __shared__ float lsq[5][64];
    #pragma unroll
    for (int nt = 0; nt < 4; ++nt) {
        float a = ss[nt], b = sq[nt];
        a += __shfl_xor(a, 16); a += __shfl_xor(a, 32);
        b += __shfl_xor(b, 16); b += __shfl_xor(b, 32);
        if (lane < 16) { lsum[wblk][nt * 16 + r16] = a; lsq[wblk][nt * 16 + r16] = b; }
    }
    __syncthreads();
    if (threadIdx.x < 64) {
        float a = 0.f, b = 0.f;
        #pragma unroll
        for (int w = 0; w < 5; ++w) { a += lsum[w][threadIdx.x]; b += lsq[w][threadIdx.x]; }
        dstparts[threadIdx.x] = a;
        dstparts[64 + threadIdx.x] = b;
    }
}

// f32 [N][32] -> bf16 [N][32] (one-shot pre-cast for conv1 gathers)
__global__ __launch_bounds__(256) void cast_feats(const float* __restrict__ in,
                                                  unsigned short* __restrict__ outp)
{
    const int i = (blockIdx.x * 256 + threadIdx.x) * 8;
    float4 f0 = ((const float4*)(in + i))[0];
    float4 f1 = ((const float4*)(in + i))[1];
    short8 v;
    v[0] = f2bf(f0.x); v[1] = f2bf(f0.y); v[2] = f2bf(f0.z); v[3] = f2bf(f0.w);
    v[4] = f2bf(f1.x); v[5] = f2bf(f1.y); v[6] = f2bf(f1.z); v[7] = f2bf(f1.w);
    *reinterpret_cast<short8*>(outp + i) = v;
}

// Pack conv1 weights (f32 [9][32][64]) into B-fragment layout bf16.
__global__ void prepack_w32(const float* __restrict__ W1, const float* __restrict__ W2,
                            unsigned short* __restrict__ P1, unsigned short* __restrict__ P2)
{
    int s = blockIdx.x / 9, k = blockIdx.x % 9, l = threadIdx.x;
    const float* W = s ? W2 : W1;
    unsigned short* P = s ? P2 : P1;
    int g = l >> 4, r16 = l & 15;
    for (int nt = 0; nt < 4; ++nt)
        for (int i = 0; i < 8; ++i) {
            int c = g * 8 + i, j = nt * 16 + r16;
            P[(((size_t)k * 4 + nt) * 64 + l) * 8 + i] =
                (unsigned short)f2bf(W[((size_t)k * 32 + c) * 64 + j]);
        }
}

// Stage 1: parallel partial reduce of parts[br][GX][128] -> atomicAdd acc[br][128].
__global__ __launch_bounds__(256) void bn_reduce1(const float* __restrict__ parts,
                                                  float* __restrict__ acc)
{
    const int br = blockIdx.y;
    const float* P = parts + (size_t)br * GX * 128;
    const int col = threadIdx.x & 127, seg = threadIdx.x >> 7;   // 2 row-segments
    const int r0 = blockIdx.x * 26;                              // 50 blocks x 26 rows >= 1256
    float s = 0.f;
    for (int i = r0 + seg; i < r0 + 26 && i < GX; i += 2)
        s += P[(size_t)i * 128 + col];
    __shared__ float red[2][128];
    red[seg][col] = s;
    __syncthreads();
    if (seg == 0) atomicAdd(acc + (size_t)br * 128 + col, red[0][col] + red[1][col]);
}

// Stage 2: BN finalize a = g*rsqrt(var+eps), c = b - mean*a (both branches).
__global__ void bn_fin2(const float* __restrict__ acc,
                        const float* g_0, const float* b_0, float* a_0, float* c_0,
                        const float* g_1, const float* b_1, float* a_1, float* c_1)
{
    const int br = blockIdx.x, j = threadIdx.x;
    const float inv_n = 1.f / (float)NVOX;
    float m = acc[br * 128 + j] * inv_n;
    float v = acc[br * 128 + 64 + j] * inv_n - m * m;
    const float* g = br ? g_1 : g_0;
    const float* b = br ? b_1 : b_0;
    float* a = br ? a_1 : a_0;
    float* c = br ? c_1 : c_0;
    float av = g[j] * rsqrtf(v + 1e-5f);
    a[j] = av;
    c[j] = b[j] - m * av;
}

// Fold BN affine into conv2 weights, emit packed bf16 B-fragments + f32 bias.
__global__ void wtrans(const float* W0, const float* a0v, const float* c0v, unsigned short* P0, float* bias0,
                       const float* W1, const float* a1v, const float* c1v, unsigned short* P1, float* bias1)
{
    int s = blockIdx.x / 9, k = blockIdx.x % 9, l = threadIdx.x;
    const float* W  = s ? W1 : W0;
    const float* av = s ? a1v : a0v;
    const float* cv = s ? c1v : c0v;
    unsigned short* P = s ? P1 : P0;
    float* bias = s ? bias1 : bias0;
    int g = l >> 4, r16 = l & 15;
    for (int ch = 0; ch < 2; ++ch)
        for (int nt = 0; nt < 4; ++nt)
            for (int i = 0; i < 8; ++i) {
                int c = ch * 32 + g * 8 + i, j = nt * 16 + r16;
                P[((((size_t)k * 2 + ch) * 4 + nt) * 64 + l) * 8 + i] =
                    (unsigned short)f2bf(av[c] * W[((size_t)k * 64 + c) * 64 + j]);
            }
    float bs = 0.f;
    for (int c = 0; c < 64; ++c) bs += cv[c] * W[((size_t)k * 64 + c) * 64 + l];
    bias[k * 64 + l] = bs;
}

// Pack bias [9][64] f32 into validity-MFMA B-fragment layout (K=32, 9 live rows).
__global__ void wpack_bias(const float* bias0, unsigned short* B0,
                           const float* bias1, unsigned short* B1)
{
    int s = blockIdx.x, l = threadIdx.x;
    const float* bias = s ? bias1 : bias0;
    unsigned short* B = s ? B1 : B0;
    int g = l >> 4, r16 = l & 15;
    for (int nt = 0; nt < 4; ++nt)
        for (int i = 0; i < 8; ++i) {
            int k9 = g * 8 + i;
            B[((size_t)nt * 64 + l) * 8 + i] =
                k9 < 9 ? (unsigned short)f2bf(bias[k9 * 64 + nt * 16 + r16]) : (unsigned short)0;
        }
}

// out = a2*r2 + c2 + a02*sc2 + c02, 8 elements per thread (vectorized).
__global__ __launch_bounds__(256) void final_k8(
    float* __restrict__ out, const __hip_bfloat16* __restrict__ sc2,
    const float* __restrict__ a2, const float* __restrict__ c2,
    const float* __restrict__ a02, const float* __restrict__ c02)
{
    const int i = (blockIdx.x * 256 + threadIdx.x) * 8;
    const int ch0 = i & 63;                      // multiple of 8
    float4 r0 = ((const float4*)(out + i))[0];
    float4 r1 = ((const float4*)(out + i))[1];
    short8 s = *reinterpret_cast<const short8*>((const unsigned short*)sc2 + i);
    float rr[8] = {r0.x, r0.y, r0.z, r0.w, r1.x, r1.y, r1.z, r1.w};
    float res[8];
    #pragma unroll
    for (int j = 0; j < 8; ++j) {
        int ch = ch0 + j;
        res[j] = a2[ch] * rr[j] + c2[ch] + a02[ch] * bfu((unsigned short)s[j]) + c02[ch];
    }
    float4 o0 = {res[0], res[1], res[2], res[3]};
    float4 o1 = {res[4], res[5], res[6], res[7]};
    ((float4*)(out + i))[0] = o0;
    ((float4*)(out + i))[1] = o1;
}

extern "C" void kernel_launch(void* const* d_in, const int* in_sizes, int n_in,
                              void* d_out, int out_size, void* d_ws, size_t ws_size,
                              hipStream_t stream)
{
    const float* feats = (const float*)d_in[0];
    const int*   nbr_a = (const int*)d_in[1];
    const int*   nbr_b = (const int*)d_in[2];
    const float* W1    = (const float*)d_in[3];
    const float* W1_2  = (const float*)d_in[4];
    const float* W2    = (const float*)d_in[5];
    const float* W3    = (const float*)d_in[6];
    const float* g0    = (const float*)d_in[7];
    const float* b0    = (const float*)d_in[8];
    const float* g0_2  = (const float*)d_in[9];
    const float* b0_2  = (const float*)d_in[10];
    const float* g1    = (const float*)d_in[11];
    const float* b1    = (const float*)d_in[12];
    const float* g2    = (const float*)d_in[13];
    const float* b2    = (const float*)d_in[14];

    char* ws = (char*)d_ws;
    size_t off = 0;
    auto alloc = [&](size_t bytes) { void* p = ws + off; off += (bytes + 255) & ~(size_t)255; return p; };
    __hip_bfloat16* sc1 = (__hip_bfloat16*)alloc((size_t)NVOX * CO * 2);
    __hip_bfloat16* r1  = (__hip_bfloat16*)alloc((size_t)NVOX * CO * 2);
    __hip_bfloat16* sc2 = (__hip_bfloat16*)alloc((size_t)NVOX * CO * 2);
    // bf16 feats (12.8 MB) aliased into sc2's buffer (25.6 MB): read only during
    // pass 1; sc2 is fully overwritten by pass 2 afterwards.
    unsigned short* featsbf = (unsigned short*)sc2;
    unsigned short* P1a = (unsigned short*)alloc((size_t)9 * 4 * 64 * 8 * 2);       // conv1 sc weights
    unsigned short* P1b = (unsigned short*)alloc((size_t)9 * 4 * 64 * 8 * 2);       // conv1 r weights
    unsigned short* P2a = (unsigned short*)alloc((size_t)9 * 2 * 4 * 64 * 8 * 2);   // conv2 sc folded
    unsigned short* P2b = (unsigned short*)alloc((size_t)9 * 2 * 4 * 64 * 8 * 2);   // conv2 r folded
    unsigned short* Bba = (unsigned short*)alloc((size_t)4 * 64 * 8 * 2);           // bias frags sc
    unsigned short* Bbb = (unsigned short*)alloc((size_t)4 * 64 * 8 * 2);           // bias frags r
    float* bias_sc = (float*)alloc(9 * 64 * 4);
    float* bias_r  = (float*)alloc(9 * 64 * 4);
    float* parts1  = (float*)alloc((size_t)2 * GX * 128 * 4);
    float* parts2  = (float*)alloc((size_t)2 * GX * 128 * 4);
    float* accs    = (float*)alloc(2 * 2 * 128 * 4);
    float* accA = accs, *accB = accs + 256;
    float* bn = (float*)alloc(8 * 64 * 4);
    float* a0 = bn,        *c0 = bn + 64;
    float* a1 = bn + 128,  *c1 = bn + 192;
    float* a02 = bn + 256, *c02 = bn + 320;
    float* a2 = bn + 384,  *c2 = bn + 448;

    hipMemsetAsync(accs, 0, 2 * 2 * 128 * 4, stream);

    const dim3 cgrid(GX, 2);     // 1256 physical blocks x 2 branches (6 empty/branch)
    const dim3 cblk(320);        // 5 waves per block
    const dim3 rgrid(50, 2);     // bn stage-1 reduce

    cast_feats<<<3125, 256, 0, stream>>>(feats, featsbf);
    prepack_w32<<<18, 64, 0, stream>>>(W1, W2, P1a, P1b);

    // pass 1: conv1 both branches (bf16 input, lrelu, partial stats)
    conv_mfma2<32, true, false, true, true><<<cgrid, cblk, 0, stream>>>(
        featsbf, featsbf, nbr_a, nbr_b, P1a, P1b, nullptr, nullptr,
        sc1, r1, parts1);
    // BN1: parallel reduce + finalize; fold into conv2 weights; pack bias frags
    bn_reduce1<<<rgrid, 256, 0, stream>>>(parts1, accA);
    bn_fin2<<<2, 64, 0, stream>>>(accA, g0, b0, a0, c0, g1, b1, a1, c1);
    wtrans<<<18, 64, 0, stream>>>(W1_2, a0, c0, P2a, bias_sc, W3, a1, c1, P2b, bias_r);
    wpack_bias<<<2, 64, 0, stream>>>(bias_sc, Bba, bias_r, Bbb);
    // pass 2: conv2 both branches (bf16 input, bias, partial stats)
    conv_mfma2<64, false, true, true, false><<<cgrid, cblk, 0, stream>>>(
        (const unsigned short*)sc1, (const unsigned short*)r1, nbr_b, nbr_a,
        P2a, P2b, Bba, Bbb, sc2, d_out, parts2);
    // BN2: parallel reduce + finalize + final fused add
    bn_reduce1<<<rgrid, 256, 0, stream>>>(parts2, accB);
    bn_fin2<<<2, 64, 0, stream>>>(accB, g0_2, b0_2, a02, c02, g2, b2, a2, c2);
    final_k8<<<6250, 256, 0, stream>>>((float*)d_out, sc2, a2, c2, a02, c02);
}

// Round 13
// 268.696 us; speedup vs baseline: 1.5270x; 1.1230x over previous
//
#include <hip/hip_runtime.h>
#include <hip/hip_bf16.h>

#define NVOX 200000
#define CO 64

typedef short short8 __attribute__((ext_vector_type(8)));
typedef float f32x4 __attribute__((ext_vector_type(4)));

static __device__ __forceinline__ short f2bf(float f) {
    __hip_bfloat16 h = __float2bfloat16(f);
    return __builtin_bit_cast(short, h);
}
static __device__ __forceinline__ float bfu(unsigned short u) {
    union { unsigned int i; float f; } x; x.i = ((unsigned int)u) << 16; return x.f;
}

// Implicit-GEMM submanifold sparse conv via MFMA 16x16x32 bf16.
// One wave owns 32 voxels = 2 M-tiles of 16; 6250 waves per branch; both
// branches in ONE dispatch (blockIdx.y). nbr indices preloaded; k-loop fully
// unrolled (k outer, B-fragments loaded once per k for both voxel tiles) --
// this exact structure measured 82us/dispatch (round 11 profile).
// Stats: wave shfl-reduce -> LDS block-reduce -> per-block partial write
// (no atomics; bn_reduce1 kernel reduces the 1250 partials per branch).
template<int CIN, bool LRELU, bool BIAS, bool OUT0_BF16, bool OUT1_BF16>
__global__ __launch_bounds__(320, 4) void conv_mfma2(
    const unsigned short* __restrict__ xin0, const unsigned short* __restrict__ xin1,
    const int*  __restrict__ nbr0, const int* __restrict__ nbr1,
    const unsigned short* __restrict__ pack0, const unsigned short* __restrict__ pack1,
    const unsigned short* __restrict__ biasB0, const unsigned short* __restrict__ biasB1,
    void* __restrict__ out0, void* __restrict__ out1,
    float* __restrict__ parts)                     // [2][1250][128]
{
    constexpr int CHN = CIN / 32;
    const int br = blockIdx.y;
    const unsigned short* xin    = br ? xin1 : xin0;
    const int* nbr               = br ? nbr1 : nbr0;
    const unsigned short* bpack  = br ? pack1 : pack0;
    const unsigned short* biasB  = br ? biasB1 : biasB0;
    void* outp                   = br ? out1 : out0;
    const bool OUT_BF16          = br ? OUT1_BF16 : OUT0_BF16;

    const int lane = threadIdx.x & 63;
    const int wblk = threadIdx.x >> 6;            // 0..4 (5 waves/block)
    const int wv   = blockIdx.x * 5 + wblk;       // 0..6249, exact
    const int gbase = wv * 32;                    // 32 voxels per wave
    const int g = lane >> 4, r16 = lane & 15;

    // Preload all neighbor indices.
    int iv[2][9];
    #pragma unroll
    for (int t = 0; t < 2; ++t)
        #pragma unroll
        for (int k = 0; k < 9; ++k)
            iv[t][k] = nbr[k * NVOX + gbase + t * 16 + r16];

    f32x4 acc[2][4];
    #pragma unroll
    for (int t = 0; t < 2; ++t)
        #pragma unroll
        for (int nt = 0; nt < 4; ++nt)
            acc[t][nt] = (f32x4){0.f, 0.f, 0.f, 0.f};

    #pragma unroll
    for (int k = 0; k < 9; ++k) {
        short8 bf[CHN][4];
        #pragma unroll
        for (int ch = 0; ch < CHN; ++ch)
            #pragma unroll
            for (int nt = 0; nt < 4; ++nt)
                bf[ch][nt] = *reinterpret_cast<const short8*>(
                    bpack + ((((size_t)k * CHN + ch) * 4 + nt) * 64 + lane) * 8);
        #pragma unroll
        for (int t = 0; t < 2; ++t) {
            const int ivk = iv[t][k];
            const int ivt = ivk < 0 ? 0 : ivk;
            #pragma unroll
            for (int ch = 0; ch < CHN; ++ch) {
                short8 av = *reinterpret_cast<const short8*>(
                    xin + (size_t)ivt * CIN + ch * 32 + g * 8);
                if (ivk < 0) { short8 z = {0,0,0,0,0,0,0,0}; av = z; }
                #pragma unroll
                for (int nt = 0; nt < 4; ++nt)
                    acc[t][nt] = __builtin_amdgcn_mfma_f32_16x16x32_bf16(av, bf[ch][nt], acc[t][nt], 0, 0, 0);
            }
        }
    }

    if (BIAS) {
        short8 bb[4];
        #pragma unroll
        for (int nt = 0; nt < 4; ++nt)
            bb[nt] = *reinterpret_cast<const short8*>(biasB + ((size_t)nt * 64 + lane) * 8);
        #pragma unroll
        for (int t = 0; t < 2; ++t) {
            unsigned vmask = 0;
            #pragma unroll
            for (int k = 0; k < 9; ++k) vmask |= (iv[t][k] >= 0 ? 1u : 0u) << k;
            short8 vf;
            #pragma unroll
            for (int i = 0; i < 8; ++i) {
                int k9 = g * 8 + i;
                vf[i] = (k9 < 9 && ((vmask >> k9) & 1u)) ? (short)0x3F80 : (short)0;
            }
            #pragma unroll
            for (int nt = 0; nt < 4; ++nt)
                acc[t][nt] = __builtin_amdgcn_mfma_f32_16x16x32_bf16(vf, bb[nt], acc[t][nt], 0, 0, 0);
        }
    }

    // Epilogue: lrelu, store, per-channel stats.
    float ss[4] = {0,0,0,0}, sq[4] = {0,0,0,0};
    #pragma unroll
    for (int t = 0; t < 2; ++t)
        #pragma unroll
        for (int nt = 0; nt < 4; ++nt)
            #pragma unroll
            for (int rr = 0; rr < 4; ++rr) {
                float val = acc[t][nt][rr];
                if (LRELU) val = val > 0.f ? val : 0.01f * val;
                ss[nt] += val; sq[nt] += val * val;
                const size_t o = (size_t)(gbase + t * 16 + g * 4 + rr) * CO + nt * 16 + r16;
                if (OUT_BF16) ((__hip_bfloat16*)outp)[o] = __float2bfloat16(val);
                else          ((float*)outp)[o] = val;
            }

    // Wave reduce (4 lane-groups sharing r16) -> LDS block reduce ->
    // per-block partial write (no atomics).
    __shared__ float lsum[5][64];
    __shared__ float lsq[5][64];
    #pragma unroll
    for (int nt = 0; nt < 4; ++nt) {
        float a = ss[nt], b = sq[nt];
        a += __shfl_xor(a, 16); a += __shfl_xor(a, 32);
        b += __shfl_xor(b, 16); b += __shfl_xor(b, 32);
        if (lane < 16) { lsum[wblk][nt * 16 + r16] = a; lsq[wblk][nt * 16 + r16] = b; }
    }
    __syncthreads();
    if (threadIdx.x < 64) {
        float a = 0.f, b = 0.f;
        #pragma unroll
        for (int w = 0; w < 5; ++w) { a += lsum[w][threadIdx.x]; b += lsq[w][threadIdx.x]; }
        float* dst = parts + ((size_t)blockIdx.y * gridDim.x + blockIdx.x) * 128;
        dst[threadIdx.x] = a;
        dst[64 + threadIdx.x] = b;
    }
}

// f32 [N][32] -> bf16 [N][32] (one-shot pre-cast for conv1 gathers)
__global__ __launch_bounds__(256) void cast_feats(const float* __restrict__ in,
                                                  unsigned short* __restrict__ outp)
{
    const int i = (blockIdx.x * 256 + threadIdx.x) * 8;
    float4 f0 = ((const float4*)(in + i))[0];
    float4 f1 = ((const float4*)(in + i))[1];
    short8 v;
    v[0] = f2bf(f0.x); v[1] = f2bf(f0.y); v[2] = f2bf(f0.z); v[3] = f2bf(f0.w);
    v[4] = f2bf(f1.x); v[5] = f2bf(f1.y); v[6] = f2bf(f1.z); v[7] = f2bf(f1.w);
    *reinterpret_cast<short8*>(outp + i) = v;
}

// Pack conv1 weights (f32 [9][32][64]) into B-fragment layout bf16.
__global__ void prepack_w32(const float* __restrict__ W1, const float* __restrict__ W2,
                            unsigned short* __restrict__ P1, unsigned short* __restrict__ P2)
{
    int s = blockIdx.x / 9, k = blockIdx.x % 9, l = threadIdx.x;
    const float* W = s ? W2 : W1;
    unsigned short* P = s ? P2 : P1;
    int g = l >> 4, r16 = l & 15;
    for (int nt = 0; nt < 4; ++nt)
        for (int i = 0; i < 8; ++i) {
            int c = g * 8 + i, j = nt * 16 + r16;
            P[(((size_t)k * 4 + nt) * 64 + l) * 8 + i] =
                (unsigned short)f2bf(W[((size_t)k * 32 + c) * 64 + j]);
        }
}

// Stage 1: parallel partial reduce of parts[br][1250][128] -> atomicAdd acc[br][128].
// 50 blocks x 25 rows = 1250 exact.
__global__ __launch_bounds__(256) void bn_reduce1(const float* __restrict__ parts,
                                                  float* __restrict__ acc)
{
    const int br = blockIdx.y;
    const float* P = parts + (size_t)br * 1250 * 128;
    const int col = threadIdx.x & 127, seg = threadIdx.x >> 7;   // 2 row-segments
    const int r0 = blockIdx.x * 25;
    float s = 0.f;
    for (int i = r0 + seg; i < r0 + 25; i += 2)
        s += P[(size_t)i * 128 + col];
    __shared__ float red[2][128];
    red[seg][col] = s;
    __syncthreads();
    if (seg == 0) atomicAdd(acc + (size_t)br * 128 + col, red[0][col] + red[1][col]);
}

// Stage 2: BN finalize a = g*rsqrt(var+eps), c = b - mean*a (both branches).
__global__ void bn_fin2(const float* __restrict__ acc,
                        const float* g_0, const float* b_0, float* a_0, float* c_0,
                        const float* g_1, const float* b_1, float* a_1, float* c_1)
{
    const int br = blockIdx.x, j = threadIdx.x;
    const float inv_n = 1.f / (float)NVOX;
    float m = acc[br * 128 + j] * inv_n;
    float v = acc[br * 128 + 64 + j] * inv_n - m * m;
    const float* g = br ? g_1 : g_0;
    const float* b = br ? b_1 : b_0;
    float* a = br ? a_1 : a_0;
    float* c = br ? c_1 : c_0;
    float av = g[j] * rsqrtf(v + 1e-5f);
    a[j] = av;
    c[j] = b[j] - m * av;
}

// Fold BN affine into conv2 weights, emit packed bf16 B-fragments + f32 bias.
__global__ void wtrans(const float* W0, const float* a0v, const float* c0v, unsigned short* P0, float* bias0,
                       const float* W1, const float* a1v, const float* c1v, unsigned short* P1, float* bias1)
{
    int s = blockIdx.x / 9, k = blockIdx.x % 9, l = threadIdx.x;
    const float* W  = s ? W1 : W0;
    const float* av = s ? a1v : a0v;
    const float* cv = s ? c1v : c0v;
    unsigned short* P = s ? P1 : P0;
    float* bias = s ? bias1 : bias0;
    int g = l >> 4, r16 = l & 15;
    for (int ch = 0; ch < 2; ++ch)
        for (int nt = 0; nt < 4; ++nt)
            for (int i = 0; i < 8; ++i) {
                int c = ch * 32 + g * 8 + i, j = nt * 16 + r16;
                P[((((size_t)k * 2 + ch) * 4 + nt) * 64 + l) * 8 + i] =
                    (unsigned short)f2bf(av[c] * W[((size_t)k * 64 + c) * 64 + j]);
            }
    float bs = 0.f;
    for (int c = 0; c < 64; ++c) bs += cv[c] * W[((size_t)k * 64 + c) * 64 + l];
    bias[k * 64 + l] = bs;
}

// Pack bias [9][64] f32 into validity-MFMA B-fragment layout (K=32, 9 live rows).
__global__ void wpack_bias(const float* bias0, unsigned short* B0,
                           const float* bias1, unsigned short* B1)
{
    int s = blockIdx.x, l = threadIdx.x;
    const float* bias = s ? bias1 : bias0;
    unsigned short* B = s ? B1 : B0;
    int g = l >> 4, r16 = l & 15;
    for (int nt = 0; nt < 4; ++nt)
        for (int i = 0; i < 8; ++i) {
            int k9 = g * 8 + i;
            B[((size_t)nt * 64 + l) * 8 + i] =
                k9 < 9 ? (unsigned short)f2bf(bias[k9 * 64 + nt * 16 + r16]) : (unsigned short)0;
        }
}

// out = a2*r2 + c2 + a02*sc2 + c02, 8 elements per thread (vectorized).
__global__ __launch_bounds__(256) void final_k8(
    float* __restrict__ out, const __hip_bfloat16* __restrict__ sc2,
    const float* __restrict__ a2, const float* __restrict__ c2,
    const float* __restrict__ a02, const float* __restrict__ c02)
{
    const int i = (blockIdx.x * 256 + threadIdx.x) * 8;
    const int ch0 = i & 63;                      // multiple of 8
    float4 r0 = ((const float4*)(out + i))[0];
    float4 r1 = ((const float4*)(out + i))[1];
    short8 s = *reinterpret_cast<const short8*>((const unsigned short*)sc2 + i);
    float rr[8] = {r0.x, r0.y, r0.z, r0.w, r1.x, r1.y, r1.z, r1.w};
    float res[8];
    #pragma unroll
    for (int j = 0; j < 8; ++j) {
        int ch = ch0 + j;
        res[j] = a2[ch] * rr[j] + c2[ch] + a02[ch] * bfu((unsigned short)s[j]) + c02[ch];
    }
    float4 o0 = {res[0], res[1], res[2], res[3]};
    float4 o1 = {res[4], res[5], res[6], res[7]};
    ((float4*)(out + i))[0] = o0;
    ((float4*)(out + i))[1] = o1;
}

extern "C" void kernel_launch(void* const* d_in, const int* in_sizes, int n_in,
                              void* d_out, int out_size, void* d_ws, size_t ws_size,
                              hipStream_t stream)
{
    const float* feats = (const float*)d_in[0];
    const int*   nbr_a = (const int*)d_in[1];
    const int*   nbr_b = (const int*)d_in[2];
    const float* W1    = (const float*)d_in[3];
    const float* W1_2  = (const float*)d_in[4];
    const float* W2    = (const float*)d_in[5];
    const float* W3    = (const float*)d_in[6];
    const float* g0    = (const float*)d_in[7];
    const float* b0    = (const float*)d_in[8];
    const float* g0_2  = (const float*)d_in[9];
    const float* b0_2  = (const float*)d_in[10];
    const float* g1    = (const float*)d_in[11];
    const float* b1    = (const float*)d_in[12];
    const float* g2    = (const float*)d_in[13];
    const float* b2    = (const float*)d_in[14];

    char* ws = (char*)d_ws;
    size_t off = 0;
    auto alloc = [&](size_t bytes) { void* p = ws + off; off += (bytes + 255) & ~(size_t)255; return p; };
    __hip_bfloat16* sc1 = (__hip_bfloat16*)alloc((size_t)NVOX * CO * 2);
    __hip_bfloat16* r1  = (__hip_bfloat16*)alloc((size_t)NVOX * CO * 2);
    __hip_bfloat16* sc2 = (__hip_bfloat16*)alloc((size_t)NVOX * CO * 2);
    // bf16 feats (12.8 MB) aliased into sc2's buffer (25.6 MB): read only during
    // pass 1; sc2 is fully overwritten by pass 2 afterwards.
    unsigned short* featsbf = (unsigned short*)sc2;
    unsigned short* P1a = (unsigned short*)alloc((size_t)9 * 4 * 64 * 8 * 2);       // conv1 sc weights
    unsigned short* P1b = (unsigned short*)alloc((size_t)9 * 4 * 64 * 8 * 2);       // conv1 r weights
    unsigned short* P2a = (unsigned short*)alloc((size_t)9 * 2 * 4 * 64 * 8 * 2);   // conv2 sc folded
    unsigned short* P2b = (unsigned short*)alloc((size_t)9 * 2 * 4 * 64 * 8 * 2);   // conv2 r folded
    unsigned short* Bba = (unsigned short*)alloc((size_t)4 * 64 * 8 * 2);           // bias frags sc
    unsigned short* Bbb = (unsigned short*)alloc((size_t)4 * 64 * 8 * 2);           // bias frags r
    float* bias_sc = (float*)alloc(9 * 64 * 4);
    float* bias_r  = (float*)alloc(9 * 64 * 4);
    float* parts1  = (float*)alloc((size_t)2 * 1250 * 128 * 4);
    float* parts2  = (float*)alloc((size_t)2 * 1250 * 128 * 4);
    float* accs    = (float*)alloc(2 * 2 * 128 * 4);
    float* accA = accs, *accB = accs + 256;
    float* bn = (float*)alloc(8 * 64 * 4);
    float* a0 = bn,        *c0 = bn + 64;
    float* a1 = bn + 128,  *c1 = bn + 192;
    float* a02 = bn + 256, *c02 = bn + 320;
    float* a2 = bn + 384,  *c2 = bn + 448;

    hipMemsetAsync(accs, 0, 2 * 2 * 128 * 4, stream);

    const dim3 cgrid(1250, 2);   // 6250 waves per branch x 2 branches, exact
    const dim3 cblk(320);        // 5 waves per block
    const dim3 rgrid(50, 2);     // bn stage-1 reduce (50 x 25 rows = 1250)

    cast_feats<<<3125, 256, 0, stream>>>(feats, featsbf);
    prepack_w32<<<18, 64, 0, stream>>>(W1, W2, P1a, P1b);

    // pass 1: conv1 both branches (bf16 input, lrelu, partial stats)
    conv_mfma2<32, true, false, true, true><<<cgrid, cblk, 0, stream>>>(
        featsbf, featsbf, nbr_a, nbr_b, P1a, P1b, nullptr, nullptr,
        sc1, r1, parts1);
    // BN1: parallel reduce + finalize; fold into conv2 weights; pack bias frags
    bn_reduce1<<<rgrid, 256, 0, stream>>>(parts1, accA);
    bn_fin2<<<2, 64, 0, stream>>>(accA, g0, b0, a0, c0, g1, b1, a1, c1);
    wtrans<<<18, 64, 0, stream>>>(W1_2, a0, c0, P2a, bias_sc, W3, a1, c1, P2b, bias_r);
    wpack_bias<<<2, 64, 0, stream>>>(bias_sc, Bba, bias_r, Bbb);
    // pass 2: conv2 both branches (bf16 input, bias, partial stats)
    conv_mfma2<64, false, true, true, false><<<cgrid, cblk, 0, stream>>>(
        (const unsigned short*)sc1, (const unsigned short*)r1, nbr_b, nbr_a,
        P2a, P2b, Bba, Bbb, sc2, d_out, parts2);
    // BN2: parallel reduce + finalize + final fused add
    bn_reduce1<<<rgrid, 256, 0, stream>>>(parts2, accB);
    bn_fin2<<<2, 64, 0, stream>>>(accB, g0_2, b0_2, a02, c02, g2, b2, a2, c2);
    final_k8<<<6250, 256, 0, stream>>>((float*)d_out, sc2, a2, c2, a02, c02);
}